// Round 7
// baseline (202.680 us; speedup 1.0000x reference)
//
#include <hip/hip_runtime.h>

#define T 256
#define CH 8192          // binned-path chunk: 32 KB LDS
#define SHIFT 13         // log2(CH)
#define CH2 16384        // fallback (round-5) chunk
#define BB 512           // binning blocks
#define WPB 4            // waves per block (T/64)
#define NW (BB * WPB)    // total binning waves = 2048
#define PMAX 16

// ============================ binned path (atomic-free multi-split) =============================

// per-WAVE partition counts via ballot. waveCnt[gw*16+p] for p<16 (0 beyond P).
__global__ void k_binhist(const int* __restrict__ dst, int e, int P,
                          int* __restrict__ waveCnt) {
    const int b = blockIdx.x;
    const int lane = threadIdx.x & 63;
    const int w = threadIdx.x >> 6;
    const int nv4 = e >> 2;
    const int s4 = (int)((long)b * nv4 / BB);
    const int e4 = (int)((long)(b + 1) * nv4 / BB);
    const int4* d4 = (const int4*)dst;
    int cnt = 0;   // count for partition == lane (lane < P)
    for (int ib = s4 + (w << 6); ib < e4; ib += T) {
        int i = ib + lane;
        bool ok = i < e4;
        int4 d = ok ? d4[i] : make_int4(-1, -1, -1, -1);
        int pc[4];
        pc[0] = ok ? (d.x >> SHIFT) : -1;
        pc[1] = ok ? (d.y >> SHIFT) : -1;
        pc[2] = ok ? (d.z >> SHIFT) : -1;
        pc[3] = ok ? (d.w >> SHIFT) : -1;
#pragma unroll
        for (int c = 0; c < 4; ++c) {
            int pbc = pc[c];
            for (int p = 0; p < P; ++p) {
                unsigned long long m = __ballot(pbc == p);
                if (lane == p) cnt += __popcll(m);
            }
        }
    }
    // tail (e % 4): processed by last wave of last block
    if (b == BB - 1 && w == WPB - 1) {
        int j = (nv4 << 2) + lane;
        int pbc = (j < e) ? (dst[j] >> SHIFT) : -1;
        for (int p = 0; p < P; ++p) {
            unsigned long long m = __ballot(pbc == p);
            if (lane == p) cnt += __popcll(m);
        }
    }
    if (lane < 16) waveCnt[(size_t)(b * WPB + w) * 16 + lane] = (lane < P) ? cnt : 0;
}

// single block: exclusive scan over waves per partition -> waveBase; bin starts -> binStart[17]
__global__ void k_prefix(const int* __restrict__ waveCnt,
                         int* __restrict__ waveBase, int* __restrict__ binStart) {
    __shared__ int cs[256][16];      // chunk sums -> chunk prefixes
    __shared__ int bt[16];
    __shared__ int bs[17];
    const int t = threadIdx.x;
    int loc[16];
#pragma unroll
    for (int p = 0; p < 16; ++p) loc[p] = 0;
    const int w0 = t * (NW / 256);
    for (int w = w0; w < w0 + (NW / 256); ++w)
#pragma unroll
        for (int p = 0; p < 16; ++p) loc[p] += waveCnt[(size_t)w * 16 + p];
#pragma unroll
    for (int p = 0; p < 16; ++p) cs[t][p] = loc[p];
    __syncthreads();
    if (t < 16) {   // serial exclusive scan of 256 chunk sums for partition t
        int run = 0;
        for (int u = 0; u < 256; ++u) { int v = cs[u][t]; cs[u][t] = run; run += v; }
        bt[t] = run;
    }
    __syncthreads();
    if (t == 0) {
        int acc = 0;
        for (int p = 0; p < 16; ++p) { bs[p] = acc; acc += bt[p]; }
        bs[16] = acc;
        for (int p = 0; p < 17; ++p) binStart[p] = bs[p];
    }
    __syncthreads();
    int run2[16];
#pragma unroll
    for (int p = 0; p < 16; ++p) run2[p] = cs[t][p] + bs[p];
    for (int w = w0; w < w0 + (NW / 256); ++w)
#pragma unroll
        for (int p = 0; p < 16; ++p) {
            waveBase[(size_t)w * 16 + p] = run2[p];
            run2[p] += waveCnt[(size_t)w * 16 + p];
        }
}

// placement, zero atomics: ballot-rank within wave, per-partition cursor lives in lane p's register
__global__ void k_binplace(const int* __restrict__ src, const int* __restrict__ dst,
                           int e, int P, const int* __restrict__ waveBase,
                           unsigned* __restrict__ binned) {
    const int b = blockIdx.x;
    const int lane = threadIdx.x & 63;
    const int w = threadIdx.x >> 6;
    const unsigned long long below = (1ULL << lane) - 1ULL;
    unsigned cursor = 0;
    if (lane < P) cursor = (unsigned)waveBase[(size_t)(b * WPB + w) * 16 + lane];
    const int nv4 = e >> 2;
    const int s4 = (int)((long)b * nv4 / BB);
    const int e4 = (int)((long)(b + 1) * nv4 / BB);
    const int4* d4 = (const int4*)dst;
    const int4* s4p = (const int4*)src;
    for (int ib = s4 + (w << 6); ib < e4; ib += T) {
        int i = ib + lane;
        bool ok = i < e4;
        int4 d = ok ? d4[i] : make_int4(-1, -1, -1, -1);
        int4 s = ok ? s4p[i] : make_int4(0, 0, 0, 0);
        int dc[4] = {d.x, d.y, d.z, d.w};
        int sc[4] = {s.x, s.y, s.z, s.w};
#pragma unroll
        for (int c = 0; c < 4; ++c) {
            int pbc = ok ? (dc[c] >> SHIFT) : -1;
            unsigned prec = cursor;
            int rank = 0;
            for (int p = 0; p < P; ++p) {
                unsigned long long m = __ballot(pbc == p);
                if (pbc == p) rank = (int)__popcll(m & below);
                if (lane == p) cursor += (unsigned)__popcll(m);
            }
            int pidx = ok ? pbc : 0;
            unsigned base = (unsigned)__shfl((int)prec, pidx);
            if (ok) binned[base + rank] = ((unsigned)sc[c] << SHIFT) | (unsigned)(dc[c] & (CH - 1));
        }
    }
    if (b == BB - 1 && w == WPB - 1) {   // tail, mirrors hist exactly
        int j = (nv4 << 2) + lane;
        bool ok = j < e;
        int dcv = ok ? dst[j] : -1;
        int scv = ok ? src[j] : 0;
        int pbc = ok ? (dcv >> SHIFT) : -1;
        unsigned prec = cursor;
        int rank = 0;
        for (int p = 0; p < P; ++p) {
            unsigned long long m = __ballot(pbc == p);
            if (pbc == p) rank = (int)__popcll(m & below);
            if (lane == p) cursor += (unsigned)__popcll(m);
        }
        int pidx = ok ? pbc : 0;
        unsigned base = (unsigned)__shfl((int)prec, pidx);
        if (ok) binned[base + rank] = ((unsigned)scv << SHIFT) | (unsigned)(dcv & (CH - 1));
    }
}

// degree count over bin p, slice g  (unchanged from round 6)
__global__ void k_cnt_bin(const unsigned* __restrict__ binned, const int* __restrict__ binStart,
                          int G, float* __restrict__ copies, int n) {
    const int g = blockIdx.x % G;
    const int p = blockIdx.x / G;
    __shared__ float lds[CH];
    for (int t = threadIdx.x; t < CH; t += T) lds[t] = 0.f;
    __syncthreads();
    const int s0 = binStart[p];
    const int size = binStart[p + 1] - s0;
    const int a   = s0 + (int)((long)g * size / G);
    const int bnd = s0 + (int)((long)(g + 1) * size / G);
    for (int i = a + threadIdx.x; i < bnd; i += T)
        atomicAdd(&lds[binned[i] & (CH - 1)], 1.0f);
    __syncthreads();
    const int lo = p * CH;
    const int lim = min(CH, n - lo);
    float* outp = copies + (size_t)g * n + lo;
    for (int t = threadIdx.x; t < lim; t += T) outp[t] = lds[t];
}

// weighted scatter over bin p, slice g  (unchanged from round 6)
__global__ void k_sct_bin(const unsigned* __restrict__ binned, const int* __restrict__ binStart,
                          int G, const float* __restrict__ v,
                          float* __restrict__ copies, int n) {
    const int g = blockIdx.x % G;
    const int p = blockIdx.x / G;
    __shared__ float lds[CH];
    for (int t = threadIdx.x; t < CH; t += T) lds[t] = 0.f;
    __syncthreads();
    const int s0 = binStart[p];
    const int size = binStart[p + 1] - s0;
    const int a   = s0 + (int)((long)g * size / G);
    const int bnd = s0 + (int)((long)(g + 1) * size / G);
    for (int i = a + threadIdx.x; i < bnd; i += T) {
        unsigned r = binned[i];
        atomicAdd(&lds[r & (CH - 1)], v[r >> SHIFT]);
    }
    __syncthreads();
    const int lo = p * CH;
    const int lim = min(CH, n - lo);
    float* outp = copies + (size_t)g * n + lo;
    for (int t = threadIdx.x; t < lim; t += T) outp[t] = lds[t];
}

// ===================== fallback: round-5 LDS-partition path =====================

__global__ void k_cnt_part(const int* __restrict__ dst, int e, int G,
                           float* __restrict__ copies, int n) {
    const int g = blockIdx.x % G;
    const int p = blockIdx.x / G;
    __shared__ float lds[CH2];
    for (int t = threadIdx.x; t < CH2; t += T) lds[t] = 0.f;
    __syncthreads();
    const int lo = p * CH2;
    const int nv4 = e >> 2;
    const long s4 = (long)g * nv4 / G;
    const long e4 = (long)(g + 1) * nv4 / G;
    const int4* d4 = (const int4*)dst;
    for (long i = s4 + threadIdx.x; i < e4; i += T) {
        int4 d = d4[i];
        if ((unsigned)(d.x - lo) < (unsigned)CH2) atomicAdd(&lds[d.x - lo], 1.f);
        if ((unsigned)(d.y - lo) < (unsigned)CH2) atomicAdd(&lds[d.y - lo], 1.f);
        if ((unsigned)(d.z - lo) < (unsigned)CH2) atomicAdd(&lds[d.z - lo], 1.f);
        if ((unsigned)(d.w - lo) < (unsigned)CH2) atomicAdd(&lds[d.w - lo], 1.f);
    }
    if (g == G - 1) {
        for (int j = (nv4 << 2) + threadIdx.x; j < e; j += T) {
            int d = dst[j];
            if ((unsigned)(d - lo) < (unsigned)CH2) atomicAdd(&lds[d - lo], 1.f);
        }
    }
    __syncthreads();
    const int lim = min(CH2, n - lo);
    float* outp = copies + (size_t)g * n + lo;
    for (int t = threadIdx.x; t < lim; t += T) outp[t] = lds[t];
}

__global__ void k_sct_part(const int* __restrict__ src, const int* __restrict__ dst,
                           const float* __restrict__ v, int e, int G,
                           float* __restrict__ copies, int n) {
    const int g = blockIdx.x % G;
    const int p = blockIdx.x / G;
    __shared__ float lds[CH2];
    for (int t = threadIdx.x; t < CH2; t += T) lds[t] = 0.f;
    __syncthreads();
    const int lo = p * CH2;
    const int nv4 = e >> 2;
    const long s4 = (long)g * nv4 / G;
    const long e4 = (long)(g + 1) * nv4 / G;
    const int4* d4 = (const int4*)dst;
    const int4* s4p = (const int4*)src;
    for (long i = s4 + threadIdx.x; i < e4; i += T) {
        int4 d = d4[i];
        int4 s = s4p[i];
        if ((unsigned)(d.x - lo) < (unsigned)CH2) atomicAdd(&lds[d.x - lo], v[s.x]);
        if ((unsigned)(d.y - lo) < (unsigned)CH2) atomicAdd(&lds[d.y - lo], v[s.y]);
        if ((unsigned)(d.z - lo) < (unsigned)CH2) atomicAdd(&lds[d.z - lo], v[s.z]);
        if ((unsigned)(d.w - lo) < (unsigned)CH2) atomicAdd(&lds[d.w - lo], v[s.w]);
    }
    if (g == G - 1) {
        for (int j = (nv4 << 2) + threadIdx.x; j < e; j += T) {
            int d = dst[j];
            if ((unsigned)(d - lo) < (unsigned)CH2) atomicAdd(&lds[d - lo], v[src[j]]);
        }
    }
    __syncthreads();
    const int lim = min(CH2, n - lo);
    float* outp = copies + (size_t)g * n + lo;
    for (int t = threadIdx.x; t < lim; t += T) outp[t] = lds[t];
}

// ===================== fallback: global-atomic path (round-4) =====================

__global__ void k_zero(float* __restrict__ c, int total) {
    int nvec = total >> 2;
    float4* c4 = (float4*)c;
    int i = blockIdx.x * blockDim.x + threadIdx.x;
    int stride = gridDim.x * blockDim.x;
    float4 z = {0.f, 0.f, 0.f, 0.f};
    for (int j = i; j < nvec; j += stride) c4[j] = z;
    if (i < (total & 3)) c[(nvec << 2) + i] = 0.f;
}

__global__ void k_count_atomic(const int* __restrict__ dst, int e,
                               float* __restrict__ copies, int n, int kmask) {
    float* c = copies + (size_t)(blockIdx.x & kmask) * n;
    int i = blockIdx.x * blockDim.x + threadIdx.x;
    int base = i * 4;
    if (base + 4 <= e) {
        int4 d = *reinterpret_cast<const int4*>(dst + base);
        unsafeAtomicAdd(&c[d.x], 1.0f);
        unsafeAtomicAdd(&c[d.y], 1.0f);
        unsafeAtomicAdd(&c[d.z], 1.0f);
        unsafeAtomicAdd(&c[d.w], 1.0f);
    } else {
        for (int j = base; j < e; ++j) unsafeAtomicAdd(&c[dst[j]], 1.0f);
    }
}

__global__ void k_scatter_atomic(const int* __restrict__ src, const int* __restrict__ dst,
                                 const float* __restrict__ v,
                                 float* __restrict__ copies, int n, int kmask, int e) {
    float* c = copies + (size_t)(blockIdx.x & kmask) * n;
    int i = blockIdx.x * blockDim.x + threadIdx.x;
    int base = i * 4;
    if (base + 4 <= e) {
        int4 s = *reinterpret_cast<const int4*>(src + base);
        int4 d = *reinterpret_cast<const int4*>(dst + base);
        float vx = v[s.x], vy = v[s.y], vz = v[s.z], vw = v[s.w];
        unsafeAtomicAdd(&c[d.x], vx);
        unsafeAtomicAdd(&c[d.y], vy);
        unsafeAtomicAdd(&c[d.z], vz);
        unsafeAtomicAdd(&c[d.w], vw);
    } else {
        for (int j = base; j < e; ++j) unsafeAtomicAdd(&c[dst[j]], v[src[j]]);
    }
}

// ===================== node-side combine kernels (shared) =====================

__global__ void k_node1(const float* __restrict__ x, float* __restrict__ copies,
                        float* __restrict__ dinv, float* __restrict__ p,
                        int n, int K, int rz) {
    int i = blockIdx.x * blockDim.x + threadIdx.x;
    if (i < n) {
        float s = 1.0f;  // self-loop
        for (int k = 0; k < K; ++k) {
            s += copies[(size_t)k * n + i];
            if (rz) copies[(size_t)k * n + i] = 0.f;
        }
        float dv = rsqrtf(s);
        dinv[i] = dv;
        p[i] = dv * x[i];
    }
}

__global__ void k_node2(const float* __restrict__ dinv, const float* __restrict__ p,
                        float* __restrict__ copies,
                        const float* __restrict__ W1, const float* __restrict__ b1,
                        const float* __restrict__ W2,
                        float* __restrict__ q, int n, int K, int rz) {
    int i = blockIdx.x * blockDim.x + threadIdx.x;
    if (i < n) {
        float t1 = p[i];
        for (int k = 0; k < K; ++k) {
            t1 += copies[(size_t)k * n + i];
            if (rz) copies[(size_t)k * n + i] = 0.f;
        }
        float dv = dinv[i];
        float u = dv * t1;
        float h2 = 0.0f;
#pragma unroll
        for (int f = 0; f < 16; ++f) {
            float h = fmaxf(fmaf(u, W1[f], b1[f]), 0.0f);
            h2 = fmaf(h, W2[f], h2);
        }
        q[i] = dv * h2;
    }
}

__global__ void k_out(const float* __restrict__ dinv, const float* __restrict__ q,
                      const float* __restrict__ copies,
                      const float* __restrict__ b2, float* __restrict__ out, int n, int K) {
    int i = blockIdx.x * blockDim.x + threadIdx.x;
    if (i < n) {
        float t2 = q[i];
        for (int k = 0; k < K; ++k) t2 += copies[(size_t)k * n + i];
        out[i] = fmaf(dinv[i], t2, b2[0]);
    }
}

// ==============================================================================

extern "C" void kernel_launch(void* const* d_in, const int* in_sizes, int n_in,
                              void* d_out, int out_size, void* d_ws, size_t ws_size,
                              hipStream_t stream) {
    const float* x  = (const float*)d_in[0];
    const float* W1 = (const float*)d_in[1];
    const float* b1 = (const float*)d_in[2];
    const float* W2 = (const float*)d_in[3];
    const float* b2 = (const float*)d_in[4];
    const int*   ei = (const int*)d_in[5];   // [2, E] int32

    const int n = in_sizes[0];        // 100000
    const int e = in_sizes[5] / 2;    // 3200000
    const int* src = ei;
    const int* dst = ei + e;

    float* out = (float*)d_out;
    const int nb_n = (n + T - 1) / T;
    const size_t units = ws_size / 4;

    // ---- binned-path workspace layout ----
    float* dinv = (float*)d_ws;
    float* p    = dinv + n;
    float* q    = p + n;
    int* waveCnt  = (int*)(q + n);                    // NW*16
    int* waveBase = waveCnt + (size_t)NW * 16;        // NW*16
    int* binStart = waveBase + (size_t)NW * 16;       // 17
    unsigned* binned = (unsigned*)(binStart + 17);    // e
    float* copiesB = (float*)(binned + e);            // G*n

    long long fixedu = 3LL * n + 2LL * NW * 16 + 17 + e;
    long long Gll = 0;
    if (n <= (PMAX * CH) && (long long)units > fixedu)
        Gll = ((long long)units - fixedu) / n;
    int G = (int)(Gll > 48 ? 48 : Gll);
    const int P = (n + CH - 1) / CH;                  // 13 for n=100000

    if (G >= 13 && P <= PMAX) {
        // =========== binned path ===========
        const int nbpg = P * G;
        k_binhist<<<BB, T, 0, stream>>>(dst, e, P, waveCnt);
        k_prefix<<<1, T, 0, stream>>>(waveCnt, waveBase, binStart);
        k_binplace<<<BB, T, 0, stream>>>(src, dst, e, P, waveBase, binned);
        k_cnt_bin<<<nbpg, T, 0, stream>>>(binned, binStart, G, copiesB, n);
        k_node1<<<nb_n, T, 0, stream>>>(x, copiesB, dinv, p, n, G, 0);
        k_sct_bin<<<nbpg, T, 0, stream>>>(binned, binStart, G, p, copiesB, n);
        k_node2<<<nb_n, T, 0, stream>>>(dinv, p, copiesB, W1, b1, W2, q, n, G, 0);
        k_sct_bin<<<nbpg, T, 0, stream>>>(binned, binStart, G, q, copiesB, n);
        k_out<<<nb_n, T, 0, stream>>>(dinv, q, copiesB, b2, out, n, G);
        return;
    }

    // ---- fallback layout (round-5): dinv, p, q, copies ----
    float* copies = q + n;
    long long avail = (long long)units - 3LL * n;
    int G2 = (int)(avail > 0 ? avail / n : 0);
    if (G2 > 64) G2 = 64;

    if (G2 >= 16) {
        const int P2 = (n + CH2 - 1) / CH2;
        const int nb_part = P2 * G2;
        k_cnt_part<<<nb_part, T, 0, stream>>>(dst, e, G2, copies, n);
        k_node1<<<nb_n, T, 0, stream>>>(x, copies, dinv, p, n, G2, 0);
        k_sct_part<<<nb_part, T, 0, stream>>>(src, dst, p, e, G2, copies, n);
        k_node2<<<nb_n, T, 0, stream>>>(dinv, p, copies, W1, b1, W2, q, n, G2, 0);
        k_sct_part<<<nb_part, T, 0, stream>>>(src, dst, q, e, G2, copies, n);
        k_out<<<nb_n, T, 0, stream>>>(dinv, q, copies, b2, out, n, G2);
    } else {
        int K = 1;
        while (K * 2 <= 8 && (long long)(K * 2) * n <= avail) K *= 2;
        const int kmask = K - 1;
        const int e4   = (e + 3) / 4;
        const int nb_e = (e4 + T - 1) / T;
        const int nb_z = min(((K * n / 4) + T - 1) / T, 2048);

        k_zero<<<nb_z, T, 0, stream>>>(copies, K * n);
        k_count_atomic<<<nb_e, T, 0, stream>>>(dst, e, copies, n, kmask);
        k_node1<<<nb_n, T, 0, stream>>>(x, copies, dinv, p, n, K, 1);
        k_scatter_atomic<<<nb_e, T, 0, stream>>>(src, dst, p, copies, n, kmask, e);
        k_node2<<<nb_n, T, 0, stream>>>(dinv, p, copies, W1, b1, W2, q, n, K, 1);
        k_scatter_atomic<<<nb_e, T, 0, stream>>>(src, dst, q, copies, n, kmask, e);
        k_out<<<nb_n, T, 0, stream>>>(dinv, q, copies, b2, out, n, K);
    }
}